// Round 1
// 85.118 us; speedup vs baseline: 1.0559x; 1.0559x over previous
//
#include <hip/hip_runtime.h>

#define NTHREADS 256
#define N_ATOMS 1024
#define HIDDEN 64

// One block per atom (B*N = 8192 blocks), 256 threads.
// Round-3 changes vs round-2 skeleton:
//  * phase 1b is r-parallel (slot=tid>>4, r=tid&15): ONE exp per (pair,r)
//    feeds BOTH species via a signed cutoff mask qm = +cutv (type0) / -cutv
//    (type1) -> halves v_exp_f32 work and doubles pairs per iteration.
//  * phase 1a: 4 ballots, ONE atomicAdd of the summed popcounts, per-round
//    offsets by uniform prefix (removes 3 atomics + 3 shfl broadcasts).
//  * MLP tail is wave-0 only with NO block barriers: within-wave DS ops are
//    processed in order, so __builtin_amdgcn_wave_barrier() (compile-time
//    fence, zero instructions) suffices between layers. Waves 1-3 retire
//    after the phase-1b barrier. 6 -> 3 __syncthreads.
__global__ __launch_bounds__(NTHREADS) void LocalFeatureEncoder_40063454937486_kernel(
    const float* __restrict__ pos,    // [B,N,3]
    const int*   __restrict__ types,  // [B,N]
    const float* __restrict__ W1,     // [34,64]
    const float* __restrict__ b1,     // [64]
    const float* __restrict__ W2,     // [64,64]
    const float* __restrict__ b2,     // [64]
    const float* __restrict__ W3,     // [64,64]
    const float* __restrict__ b3,     // [64]
    float*       __restrict__ out)    // [B,N,64]
{
    const int a    = blockIdx.x;          // b*N + i
    const int bidx = a >> 10;             // N = 1024
    const int i    = a & (N_ATOMS - 1);
    const int tid  = threadIdx.x;
    const int lane = tid & 63;
    const int wav  = tid >> 6;

    __shared__ float qd [N_ATOMS];        // queue: distance
    __shared__ float qm [N_ATOMS];        // queue: +cutv if type0, -cutv if type1
    __shared__ float partial[4 * 32];
    __shared__ float feats[64];           // 34 used (then reused as h2)
    __shared__ float h1s[64];
    __shared__ int   cnt;

    const float* pf   = pos + (size_t)bidx * (N_ATOMS * 3);
    const int*   typb = types + (size_t)bidx * N_ATOMS;

    // ---- issue all neighbor loads BEFORE the barrier (latency overlap) ----
    const float4 p0 = *(const float4*)(pf + tid * 12);
    const float4 p1 = *(const float4*)(pf + tid * 12 + 4);
    const float4 p2 = *(const float4*)(pf + tid * 12 + 8);
    const int4   tv = *(const int4*)(typb + tid * 4);

    const float xi = pf[i * 3 + 0];
    const float yi = pf[i * 3 + 1];
    const float zi = pf[i * 3 + 2];

    if (tid == 0) cnt = 0;
    __syncthreads();                      // cnt = 0 visible

    // ---------- phase 1a: distances + stream compaction, single atomic ----------
    {
        const float px[4] = {p0.x, p0.w, p1.z, p2.y};
        const float py[4] = {p0.y, p1.x, p1.w, p2.z};
        const float pz[4] = {p0.z, p1.y, p2.x, p2.w};
        const int   tj[4] = {tv.x, tv.y, tv.z, tv.w};

        float sq[4];
        bool  pr[4];
        unsigned long long m[4];
#pragma unroll
        for (int q = 0; q < 4; ++q) {
            const int j = tid * 4 + q;
            const float dx = xi - px[q], dy = yi - py[q], dz = zi - pz[q];
            sq[q] = dx * dx + dy * dy + dz * dz;
            pr[q] = (j != i) && (sq[q] < 6.25f);
            m[q]  = __ballot(pr[q]);
        }

        const int tot = (int)(__popcll(m[0]) + __popcll(m[1]) +
                              __popcll(m[2]) + __popcll(m[3]));
        int base = 0;
        if (lane == 0 && tot) base = atomicAdd(&cnt, tot);
        base = __shfl(base, 0, 64);       // convergent broadcast

        const unsigned long long lt = (1ull << lane) - 1ull;
        int off = base;
#pragma unroll
        for (int q = 0; q < 4; ++q) {
            if (pr[q]) {
                const float d  = sqrtf(sq[q]);
                const float x  = d * 0.4f;    // d / 2.5
                const float x3 = x * x * x;
                const float cutv = 1.0f + x3 * (-10.0f + x * (15.0f - 6.0f * x));
                const int idx = off + (int)__popcll(m[q] & lt);
                qd[idx] = d;
                qm[idx] = (tj[q] == 0) ? cutv : -cutv;
            }
            off += (int)__popcll(m[q]);   // wave-uniform prefix for next round
        }
    }
    __syncthreads();
    const int n = cnt;

    // ---------- phase 1b: r-parallel RBF accumulation ----------
    {
        const int slot = tid >> 4;            // pair slot 0..15
        const int r    = tid & 15;            // RBF center 0..15
        const float c  = (float)r * (2.5f / 15.0f);

        float a0 = 0.0f, a1 = 0.0f;
        for (int e = slot; e < n; e += 16) {
            const float d    = qd[e];         // broadcast within 16-lane group
            const float mm   = qm[e];
            const float diff = d - c;
            const float ex   = __expf(-(diff * diff) * 36.0f);
            a0 = fmaf(fmaxf( mm, 0.0f), ex, a0);
            a1 = fmaf(fmaxf(-mm, 0.0f), ex, a1);
        }
        // reduce the 4 slots of this wave (lane bits 4,5)
        a0 += __shfl_xor(a0, 16, 64);  a0 += __shfl_xor(a0, 32, 64);
        a1 += __shfl_xor(a1, 16, 64);  a1 += __shfl_xor(a1, 32, 64);
        if (lane < 16) {
            partial[wav * 32 + 2 * r]     = a0;   // feature f = 2r+s
            partial[wav * 32 + 2 * r + 1] = a1;
        }
        if (tid == 0) {
            const int ti = typb[i];
            feats[0] = (ti == 0) ? 1.0f : 0.0f;
            feats[1] = (ti == 1) ? 1.0f : 0.0f;
        }
    }
    __syncthreads();

    // ---------- wave-0-only tail: finalize feats + 3-layer MLP ----------
    // All producers/consumers below live in wave 0; the LDS unit processes a
    // wave's DS ops in order, so compile-time wave_barrier fences suffice.
    if (tid < HIDDEN) {
        if (tid < 32)
            feats[2 + tid] = partial[tid] + partial[32 + tid] +
                             partial[64 + tid] + partial[96 + tid];
        __builtin_amdgcn_wave_barrier();

        float h = b1[tid];
#pragma unroll
        for (int k = 0; k < 34; k++) h = fmaf(feats[k], W1[k * HIDDEN + tid], h);
        h = h / (1.0f + __expf(-h));
        h1s[tid] = h;
        __builtin_amdgcn_wave_barrier();

        float g = b2[tid];
#pragma unroll
        for (int k = 0; k < HIDDEN; k++) g = fmaf(h1s[k], W2[k * HIDDEN + tid], g);
        g = g / (1.0f + __expf(-g));
        feats[tid] = g;                   // reuse feats as h2
        __builtin_amdgcn_wave_barrier();

        float o = b3[tid];
#pragma unroll
        for (int k = 0; k < HIDDEN; k++) o = fmaf(feats[k], W3[k * HIDDEN + tid], o);
        out[(size_t)a * HIDDEN + tid] = o;
    }
}

extern "C" void kernel_launch(void* const* d_in, const int* in_sizes, int n_in,
                              void* d_out, int out_size, void* d_ws, size_t ws_size,
                              hipStream_t stream) {
    const float* pos   = (const float*)d_in[0];
    const int*   types = (const int*)d_in[1];
    const float* W1    = (const float*)d_in[2];
    const float* b1    = (const float*)d_in[3];
    const float* W2    = (const float*)d_in[4];
    const float* b2    = (const float*)d_in[5];
    const float* W3    = (const float*)d_in[6];
    const float* b3    = (const float*)d_in[7];
    float*       out   = (float*)d_out;

    const int BN = in_sizes[1];           // B*N = 8192

    LocalFeatureEncoder_40063454937486_kernel<<<BN, NTHREADS, 0, stream>>>(
        pos, types, W1, b1, W2, b2, W3, b3, out);
}

// Round 2
// 83.598 us; speedup vs baseline: 1.0751x; 1.0182x over previous
//
#include <hip/hip_runtime.h>

#define NTHREADS 256
#define N_ATOMS 1024
#define HIDDEN 64

// One block per PAIR of atoms (grid = B*N/2 = 4096), 256 threads.
// Round-4 change vs round-3: 2-atom batching to amortize the wave-0 MLP
// tail (the dominant remaining issue cost): weights are loaded ONCE per k
// and fed to both atoms' accumulators via interleaved [k][atom] LDS state
// (ds_read_b64), halving per-atom weight-load traffic and tail instruction
// count (600 -> ~360 wave-insts/atom). Neighbor positions/types are loaded
// once per block (shared by both atoms); phase-1a uses a single PACKED
// atomicAdd (n0 | n1<<16); barriers per atom are halved.
__global__ __launch_bounds__(NTHREADS) void LocalFeatureEncoder_40063454937486_kernel(
    const float* __restrict__ pos,    // [B,N,3]
    const int*   __restrict__ types,  // [B,N]
    const float* __restrict__ W1,     // [34,64]
    const float* __restrict__ b1,     // [64]
    const float* __restrict__ W2,     // [64,64]
    const float* __restrict__ b2,     // [64]
    const float* __restrict__ W3,     // [64,64]
    const float* __restrict__ b3,     // [64]
    float*       __restrict__ out)    // [B,N,64]
{
    const int blk  = blockIdx.x;          // bidx*512 + pair
    const int bidx = blk >> 9;            // 512 pairs per batch
    const int i0   = (blk & 511) * 2;
    const int i1   = i0 + 1;
    const int tid  = threadIdx.x;
    const int lane = tid & 63;
    const int wav  = tid >> 6;

    __shared__ __align__(16) float qd[2][N_ATOMS];   // queue: distance
    __shared__ __align__(16) float qm[2][N_ATOMS];   // queue: +cutv type0 / -cutv type1
    __shared__ __align__(16) float partial[4 * 64];  // [wav][f=2r+s][atom]
    __shared__ __align__(16) float feats[34 * 2];    // [k][atom]
    __shared__ __align__(16) float h1s[HIDDEN * 2];  // [k][atom]
    __shared__ __align__(16) float h2s[HIDDEN * 2];  // [k][atom]
    __shared__ int cnt;                               // packed: n0 | n1<<16

    const float* pf   = pos + (size_t)bidx * (N_ATOMS * 3);
    const int*   typb = types + (size_t)bidx * N_ATOMS;

    // ---- issue all neighbor loads BEFORE the barrier (latency overlap) ----
    const float4 p0 = *(const float4*)(pf + tid * 12);
    const float4 p1 = *(const float4*)(pf + tid * 12 + 4);
    const float4 p2 = *(const float4*)(pf + tid * 12 + 8);
    const int4   tv = *(const int4*)(typb + tid * 4);

    const float xi0 = pf[i0 * 3 + 0], yi0 = pf[i0 * 3 + 1], zi0 = pf[i0 * 3 + 2];
    const float xi1 = pf[i1 * 3 + 0], yi1 = pf[i1 * 3 + 1], zi1 = pf[i1 * 3 + 2];

    if (tid == 0) cnt = 0;
    __syncthreads();                      // cnt = 0 visible

    // ---------- phase 1a: distances + compaction for BOTH atoms ----------
    {
        const float px[4] = {p0.x, p0.w, p1.z, p2.y};
        const float py[4] = {p0.y, p1.x, p1.w, p2.z};
        const float pz[4] = {p0.z, p1.y, p2.x, p2.w};
        const int   tj[4] = {tv.x, tv.y, tv.z, tv.w};

        float sq0[4], sq1[4];
        bool  pr0[4], pr1[4];
        unsigned long long m0[4], m1[4];
#pragma unroll
        for (int q = 0; q < 4; ++q) {
            const int j = tid * 4 + q;
            float dx = xi0 - px[q], dy = yi0 - py[q], dz = zi0 - pz[q];
            sq0[q] = dx * dx + dy * dy + dz * dz;
            dx = xi1 - px[q]; dy = yi1 - py[q]; dz = zi1 - pz[q];
            sq1[q] = dx * dx + dy * dy + dz * dz;
            pr0[q] = (j != i0) && (sq0[q] < 6.25f);
            pr1[q] = (j != i1) && (sq1[q] < 6.25f);
            m0[q]  = __ballot(pr0[q]);
            m1[q]  = __ballot(pr1[q]);
        }

        const int tot0 = (int)(__popcll(m0[0]) + __popcll(m0[1]) +
                               __popcll(m0[2]) + __popcll(m0[3]));
        const int tot1 = (int)(__popcll(m1[0]) + __popcll(m1[1]) +
                               __popcll(m1[2]) + __popcll(m1[3]));
        // single packed atomic: n0 in [15:0], n1 in [31:16] (each sums <= 1024)
        int basep = 0;
        if (lane == 0) basep = atomicAdd(&cnt, tot0 | (tot1 << 16));
        basep = __shfl(basep, 0, 64);     // convergent broadcast

        const unsigned long long lt = (1ull << lane) - 1ull;
        int off0 = basep & 0xffff;
        int off1 = (basep >> 16) & 0xffff;
#pragma unroll
        for (int q = 0; q < 4; ++q) {
            if (pr0[q]) {
                const float d  = sqrtf(sq0[q]);
                const float x  = d * 0.4f;    // d / 2.5
                const float x3 = x * x * x;
                const float cutv = 1.0f + x3 * (-10.0f + x * (15.0f - 6.0f * x));
                const int idx = off0 + (int)__popcll(m0[q] & lt);
                qd[0][idx] = d;
                qm[0][idx] = (tj[q] == 0) ? cutv : -cutv;
            }
            if (pr1[q]) {
                const float d  = sqrtf(sq1[q]);
                const float x  = d * 0.4f;
                const float x3 = x * x * x;
                const float cutv = 1.0f + x3 * (-10.0f + x * (15.0f - 6.0f * x));
                const int idx = off1 + (int)__popcll(m1[q] & lt);
                qd[1][idx] = d;
                qm[1][idx] = (tj[q] == 0) ? cutv : -cutv;
            }
            off0 += (int)__popcll(m0[q]); // wave-uniform prefix for next round
            off1 += (int)__popcll(m1[q]);
        }
    }
    __syncthreads();
    const int packed = cnt;
    const int n0   = packed & 0xffff;
    const int n1   = (packed >> 16) & 0xffff;
    const int nmax = (n0 > n1) ? n0 : n1;

    // ---------- phase 1b: r-parallel RBF accumulation, both atoms ----------
    {
        const int slot = tid >> 4;            // pair slot 0..15
        const int r    = tid & 15;            // RBF center 0..15
        const float c  = (float)r * (2.5f / 15.0f);

        float a00 = 0.0f, a10 = 0.0f;         // a<species><atom>
        float a01 = 0.0f, a11 = 0.0f;
        for (int e = slot; e < nmax; e += 16) {
            if (e < n0) {
                const float d    = qd[0][e];
                const float mm   = qm[0][e];
                const float diff = d - c;
                const float ex   = __expf(-(diff * diff) * 36.0f);
                a00 = fmaf(fmaxf( mm, 0.0f), ex, a00);
                a10 = fmaf(fmaxf(-mm, 0.0f), ex, a10);
            }
            if (e < n1) {
                const float d    = qd[1][e];
                const float mm   = qm[1][e];
                const float diff = d - c;
                const float ex   = __expf(-(diff * diff) * 36.0f);
                a01 = fmaf(fmaxf( mm, 0.0f), ex, a01);
                a11 = fmaf(fmaxf(-mm, 0.0f), ex, a11);
            }
        }
        a00 += __shfl_xor(a00, 16, 64);  a00 += __shfl_xor(a00, 32, 64);
        a10 += __shfl_xor(a10, 16, 64);  a10 += __shfl_xor(a10, 32, 64);
        a01 += __shfl_xor(a01, 16, 64);  a01 += __shfl_xor(a01, 32, 64);
        a11 += __shfl_xor(a11, 16, 64);  a11 += __shfl_xor(a11, 32, 64);
        if (lane < 16) {
            // partial[wav][f][atom], f=2r+s: 4 consecutive floats -> one b128
            const float4 v = {a00, a01, a10, a11};
            *(float4*)&partial[wav * 64 + r * 4] = v;
        }
        if (tid == 0) {
            const int t0 = typb[i0], t1 = typb[i1];
            feats[0] = (t0 == 0) ? 1.0f : 0.0f;   // k=0 (species0), atom0
            feats[1] = (t1 == 0) ? 1.0f : 0.0f;   // k=0, atom1
            feats[2] = (t0 == 1) ? 1.0f : 0.0f;   // k=1 (species1), atom0
            feats[3] = (t1 == 1) ? 1.0f : 0.0f;   // k=1, atom1
        }
    }
    __syncthreads();

    // ---------- wave-0-only tail: finalize feats + 3-layer MLP, 2 atoms ----------
    if (tid < HIDDEN) {
        if (tid < 32) {
            float2 acc      = *(const float2*)&partial[tid * 2];
            const float2 q1 = *(const float2*)&partial[ 64 + tid * 2];
            const float2 q2 = *(const float2*)&partial[128 + tid * 2];
            const float2 q3 = *(const float2*)&partial[192 + tid * 2];
            acc.x += q1.x + q2.x + q3.x;
            acc.y += q1.y + q2.y + q3.y;
            *(float2*)&feats[(2 + tid) * 2] = acc;
        }
        __builtin_amdgcn_wave_barrier();

        float h0 = b1[tid], h1v = b1[tid];
#pragma unroll
        for (int k = 0; k < 34; ++k) {
            const float w  = W1[k * HIDDEN + tid];
            const float2 f = *(const float2*)&feats[k * 2];
            h0  = fmaf(f.x, w, h0);
            h1v = fmaf(f.y, w, h1v);
        }
        h0  = h0  / (1.0f + __expf(-h0));
        h1v = h1v / (1.0f + __expf(-h1v));
        *(float2*)&h1s[tid * 2] = make_float2(h0, h1v);
        __builtin_amdgcn_wave_barrier();

        float g0 = b2[tid], g1 = b2[tid];
#pragma unroll
        for (int k = 0; k < HIDDEN; ++k) {
            const float w  = W2[k * HIDDEN + tid];
            const float2 f = *(const float2*)&h1s[k * 2];
            g0 = fmaf(f.x, w, g0);
            g1 = fmaf(f.y, w, g1);
        }
        g0 = g0 / (1.0f + __expf(-g0));
        g1 = g1 / (1.0f + __expf(-g1));
        *(float2*)&h2s[tid * 2] = make_float2(g0, g1);
        __builtin_amdgcn_wave_barrier();

        float o0 = b3[tid], o1 = b3[tid];
#pragma unroll
        for (int k = 0; k < HIDDEN; ++k) {
            const float w  = W3[k * HIDDEN + tid];
            const float2 f = *(const float2*)&h2s[k * 2];
            o0 = fmaf(f.x, w, o0);
            o1 = fmaf(f.y, w, o1);
        }
        const size_t row0 = (size_t)(bidx * N_ATOMS + i0) * HIDDEN;
        out[row0 + tid]          = o0;
        out[row0 + HIDDEN + tid] = o1;    // i1 = i0+1 -> contiguous row
    }
}

extern "C" void kernel_launch(void* const* d_in, const int* in_sizes, int n_in,
                              void* d_out, int out_size, void* d_ws, size_t ws_size,
                              hipStream_t stream) {
    const float* pos   = (const float*)d_in[0];
    const int*   types = (const int*)d_in[1];
    const float* W1    = (const float*)d_in[2];
    const float* b1    = (const float*)d_in[3];
    const float* W2    = (const float*)d_in[4];
    const float* b2    = (const float*)d_in[5];
    const float* W3    = (const float*)d_in[6];
    const float* b3    = (const float*)d_in[7];
    float*       out   = (float*)d_out;

    const int BN = in_sizes[1];           // B*N = 8192
    const int nblocks = BN >> 1;          // one block per atom pair

    LocalFeatureEncoder_40063454937486_kernel<<<nblocks, NTHREADS, 0, stream>>>(
        pos, types, W1, b1, W2, b2, W3, b3, out);
}